// Round 6
// baseline (1923.815 us; speedup 1.0000x reference)
//
#include <hip/hip_runtime.h>

typedef unsigned short ushort_t;
typedef __attribute__((ext_vector_type(8))) short bf16x8;
typedef __attribute__((ext_vector_type(4))) float f32x4;

#define BB 32
#define TT 64
#define HH 512
#define G4H 2048

__device__ __forceinline__ ushort_t f2bf(float f) {
    unsigned int u = __float_as_uint(f);
    unsigned int r = (u + 0x7fffu + ((u >> 16) & 1u)) >> 16;
    return (ushort_t)r;
}
__device__ __forceinline__ float sigf(float x) { return 1.f / (1.f + __expf(-x)); }
__device__ __forceinline__ float tanh_(float x) {
    float e = __expf(2.f * x);
    return 1.f - 2.f / (e + 1.f);
}

// ---------------- zero init (zeros vector for h0/c0) ----------------
__global__ void zero_init(float* zeros) {
    int t = threadIdx.x;
    if (t < 128) ((float4*)zeros)[t] = make_float4(0.f, 0.f, 0.f, 0.f); // 512 floats
}

// ---------------- embedding gather ----------------
__global__ void gather_rows(const int* __restrict__ idx, const float* __restrict__ emb,
                            float* __restrict__ out) {
    int row = blockIdx.x;      // 2048 rows
    int t = threadIdx.x;       // 64 threads
    int id = idx[row];
    float4 v = *(const float4*)(emb + (size_t)id * 256 + t * 4);
    *(float4*)(out + (size_t)row * 256 + t * 4) = v;
}

// ---------------- generic fp32 GEMM: C[M,N] = act(A[M,K] * B[N,K]^T + bias) ----------------
// mode 0: fp32 out, no act. mode 2: tanh then bf16 out.
__global__ __launch_bounds__(256) void gemm_f32(
    const float* __restrict__ A, int lda,
    const float* __restrict__ B, int ldb,
    const float* __restrict__ bias,
    void* __restrict__ Cv, int ldc,
    int M, int N, int K, int mode)
{
    __shared__ float As[16 * 68];
    __shared__ float Bs[16 * 68];
    const int tid = threadIdx.x;
    const int bm = blockIdx.y * 64, bn = blockIdx.x * 64;
    const int lr = tid >> 2, lk = (tid & 3) << 2;
    const int tr = (tid >> 4) << 2, tc = (tid & 15) << 2;
    float acc[4][4] = {};
    const int arow = bm + lr, brow = bn + lr;
    const bool aval = arow < M, bval = brow < N;
    const float* Ap = A + (size_t)arow * lda + lk;
    const float* Bp = B + (size_t)brow * ldb + lk;

    for (int k0 = 0; k0 < K; k0 += 16) {
        float4 av = make_float4(0.f, 0.f, 0.f, 0.f);
        float4 bv = make_float4(0.f, 0.f, 0.f, 0.f);
        if (aval) av = *(const float4*)(Ap + k0);
        if (bval) bv = *(const float4*)(Bp + k0);
        As[(lk + 0) * 68 + lr] = av.x; As[(lk + 1) * 68 + lr] = av.y;
        As[(lk + 2) * 68 + lr] = av.z; As[(lk + 3) * 68 + lr] = av.w;
        Bs[(lk + 0) * 68 + lr] = bv.x; Bs[(lk + 1) * 68 + lr] = bv.y;
        Bs[(lk + 2) * 68 + lr] = bv.z; Bs[(lk + 3) * 68 + lr] = bv.w;
        __syncthreads();
        #pragma unroll
        for (int kk = 0; kk < 16; kk++) {
            float4 a = *(const float4*)&As[kk * 68 + tr];
            float4 b = *(const float4*)&Bs[kk * 68 + tc];
            float ar[4] = {a.x, a.y, a.z, a.w};
            float br[4] = {b.x, b.y, b.z, b.w};
            #pragma unroll
            for (int i = 0; i < 4; i++)
                #pragma unroll
                for (int j = 0; j < 4; j++)
                    acc[i][j] = fmaf(ar[i], br[j], acc[i][j]);
        }
        __syncthreads();
    }
    #pragma unroll
    for (int i = 0; i < 4; i++) {
        int m = bm + tr + i;
        if (m >= M) continue;
        #pragma unroll
        for (int j = 0; j < 4; j++) {
            int n = bn + tc + j;
            if (n >= N) continue;
            float v = acc[i][j] + (bias ? bias[n] : 0.f);
            if (mode == 0) {
                ((float*)Cv)[(size_t)m * ldc + n] = v;
            } else {
                ((ushort_t*)Cv)[(size_t)m * ldc + n] = f2bf(tanh_(v));
            }
        }
    }
}

// ---------------- context mean ----------------
__global__ void mean_ctx(const float* __restrict__ e1, float* __restrict__ ctx) {
    int g = blockIdx.x * 256 + threadIdx.x; // 16384
    int b = g >> 9, u = g & 511;
    float s = 0.f;
    #pragma unroll 8
    for (int t = 0; t < TT; t++) s += e1[((size_t)b * TT + t) * HH + u];
    ctx[g] = s * (1.f / 64.f);
}

// ---------------- LSTM scan v6: tagged exchange on the plain VMEM path ----------------
// 256 blocks = 4 batch-groups (8 batches) x 64 unit-blocks (8 h-units = 32 gate rows).
// Producers publish h as TWO self-validating 4B words (tag16|hi16, tag16|lo16) with one
// global_store_dwordx2 sc0 sc1 (cache-bypass, cross-XCD coherent — proven in round 2).
// Consumers poll 16 slots with one asm batch of 16 dwordx2 sc0 sc1 loads + single waitcnt.
// Plain-VMEM path avoids the TCC-atomic serialization that limited round 5.
__global__ __launch_bounds__(256) void lstm_scan(
    const float* __restrict__ gatesX,  // [B*T][4H] precomputed x-projection (incl bias)
    const float* __restrict__ ctxAdd,  // [B][4H] or null (decoder layer0 context term)
    const float* __restrict__ Whh,     // [4H][H]
    const float* __restrict__ h0, int h0_stride,
    const float* __restrict__ c0, int c0_stride,
    float* __restrict__ out,           // [B*T][H] (plain stores; read by later kernels)
    float* __restrict__ cT,            // [B][H] or null
    uint2* __restrict__ ring,          // [T][B][H] tagged h exchange
    int tag_base)                      // layer*64; tag for step t = tag_base+t+1 (<=256)
{
    __shared__ float wlds[32 * 516];
    __shared__ float hlds[8 * 516];
    __shared__ float glds[8 * 33];
    __shared__ float clds[64];
    const int tid = threadIdx.x;
    const int bg = blockIdx.x >> 6;        // batch group 0..3
    const int ub = blockIdx.x & 63;        // unit block 0..63
    const int u0 = ub * 8;
    const int bb = (tid >> 3) & 7;         // batch within group (dot role)
    const int rr = (tid >> 6) * 8 + (tid & 7); // row 0..31 (gate = rr>>3 = wave id)
    const int grow = (rr >> 3) * HH + u0 + (rr & 7);
    const int bglob = bg * 8 + bb;

    { // stationary weights -> LDS: row = tid>>3, 64-col chunk = (tid&7)*64
        const int srow = tid >> 3, scol = (tid & 7) * 64;
        const int sg = srow >> 3, su = srow & 7;
        const float* wsrc = Whh + (size_t)(sg * HH + u0 + su) * HH + scol;
        float* wdst = &wlds[srow * 516 + scol];
        #pragma unroll
        for (int j = 0; j < 64; j += 4) *(f32x4*)(wdst + j) = *(const f32x4*)(wsrc + j);
    }
    if (tid < 64) { // c state: (bb2, uu2)
        clds[tid] = c0[(size_t)(bg * 8 + (tid >> 3)) * c0_stride + u0 + (tid & 7)];
    }
    const float xctx = ctxAdd ? ctxAdd[(size_t)bglob * G4H + grow] : 0.f;
    const int hrow = tid >> 5;             // staging role: batch row 0..7
    const int hc0 = tid & 31;              // lane within row
    const float* gxp = gatesX + (size_t)bglob * TT * G4H + grow;
    float gx_cur = gxp[0];
    float gx_nxt;

    { // stage h0 (plain loads) -> hlds
        const float* hs = h0 + (size_t)(bg * 8 + hrow) * h0_stride;
        float* hd = &hlds[hrow * 516 + hc0];
        #pragma unroll
        for (int j = 0; j < 16; j++) hd[32 * j] = hs[hc0 + 32 * j];
    }

    for (int t = 0; t < TT; t++) {
        __syncthreads();   // hlds (and prev glds consumption) ready
        // prefetch gatesX for NEXT step: full dot of slack to complete
        {
            int tn = (t + 1 < TT) ? t + 1 : t;
            gx_nxt = gxp[(size_t)tn * G4H];
        }
        // dot(h_prev[bb,:], Whh[grow,:]) -- broadcast-friendly LDS reads
        f32x4 s = {0.f, 0.f, 0.f, 0.f};
        const float* hp = &hlds[bb * 516];
        const float* wp = &wlds[rr * 516];
        #pragma unroll 8
        for (int k = 0; k < HH; k += 4) {
            f32x4 hvv = *(const f32x4*)(hp + k);
            f32x4 wv = *(const f32x4*)(wp + k);
            s.x = fmaf(hvv.x, wv.x, s.x); s.y = fmaf(hvv.y, wv.y, s.y);
            s.z = fmaf(hvv.z, wv.z, s.z); s.w = fmaf(hvv.w, wv.w, s.w);
        }
        glds[bb * 33 + rr] = gx_cur + xctx + ((s.x + s.y) + (s.z + s.w));
        __syncthreads();   // glds ready; hlds free for restage
        const unsigned int tag = (unsigned int)(tag_base + t + 1);
        if (tid < 64) {
            const int bb2 = tid >> 3, uu2 = tid & 7;
            const int bg2 = bg * 8 + bb2;
            float gi = glds[bb2 * 33 + 0 + uu2];
            float gf = glds[bb2 * 33 + 8 + uu2];
            float gg = glds[bb2 * 33 + 16 + uu2];
            float go = glds[bb2 * 33 + 24 + uu2];
            float c = sigf(gf) * clds[tid] + sigf(gi) * tanh_(gg);
            float h = sigf(go) * tanh_(c);
            clds[tid] = c;
            out[((size_t)bg2 * TT + t) * HH + u0 + uu2] = h;  // plain (kernel-boundary readers)
            unsigned int hu = __float_as_uint(h);
            uint2 w;
            w.x = (tag << 16) | (hu >> 16);
            w.y = (tag << 16) | (hu & 0xFFFFu);
            uint2* pp = ring + ((size_t)t * BB + bg2) * HH + u0 + uu2;
            asm volatile("global_store_dwordx2 %0, %1, off sc0 sc1"
                         :: "v"(pp), "v"(w) : "memory");
            if (cT && t == TT - 1) cT[(size_t)bg2 * HH + u0 + uu2] = c;
        }
        if (t + 1 < TT) {
            // poll-stage h(t): 16 slots per thread, one batched sweep per retry
            const uint2* rp = ring + ((size_t)t * BB + bg * 8 + hrow) * HH + hc0;
            uint2 q0, q1, q2, q3, q4, q5, q6, q7, q8, q9, qa, qb, qc, qd, qe, qf;
            bool ok;
            do {
                asm volatile(
                    "global_load_dwordx2 %0, %16, off sc0 sc1\n\t"
                    "global_load_dwordx2 %1, %16, off offset:256 sc0 sc1\n\t"
                    "global_load_dwordx2 %2, %16, off offset:512 sc0 sc1\n\t"
                    "global_load_dwordx2 %3, %16, off offset:768 sc0 sc1\n\t"
                    "global_load_dwordx2 %4, %16, off offset:1024 sc0 sc1\n\t"
                    "global_load_dwordx2 %5, %16, off offset:1280 sc0 sc1\n\t"
                    "global_load_dwordx2 %6, %16, off offset:1536 sc0 sc1\n\t"
                    "global_load_dwordx2 %7, %16, off offset:1792 sc0 sc1\n\t"
                    "global_load_dwordx2 %8, %16, off offset:2048 sc0 sc1\n\t"
                    "global_load_dwordx2 %9, %16, off offset:2304 sc0 sc1\n\t"
                    "global_load_dwordx2 %10, %16, off offset:2560 sc0 sc1\n\t"
                    "global_load_dwordx2 %11, %16, off offset:2816 sc0 sc1\n\t"
                    "global_load_dwordx2 %12, %16, off offset:3072 sc0 sc1\n\t"
                    "global_load_dwordx2 %13, %16, off offset:3328 sc0 sc1\n\t"
                    "global_load_dwordx2 %14, %16, off offset:3584 sc0 sc1\n\t"
                    "global_load_dwordx2 %15, %16, off offset:3840 sc0 sc1\n\t"
                    "s_waitcnt vmcnt(0)"
                    : "=&v"(q0), "=&v"(q1), "=&v"(q2), "=&v"(q3),
                      "=&v"(q4), "=&v"(q5), "=&v"(q6), "=&v"(q7),
                      "=&v"(q8), "=&v"(q9), "=&v"(qa), "=&v"(qb),
                      "=&v"(qc), "=&v"(qd), "=&v"(qe), "=&v"(qf)
                    : "v"(rp) : "memory");
                unsigned int m0 = q0.x & q1.x & q2.x & q3.x & q4.x & q5.x & q6.x & q7.x
                                & q8.x & q9.x & qa.x & qb.x & qc.x & qd.x & qe.x & qf.x;
                unsigned int o0 = q0.x | q1.x | q2.x | q3.x | q4.x | q5.x | q6.x | q7.x
                                | q8.x | q9.x | qa.x | qb.x | qc.x | qd.x | qe.x | qf.x;
                unsigned int m1 = q0.y & q1.y & q2.y & q3.y & q4.y & q5.y & q6.y & q7.y
                                & q8.y & q9.y & qa.y & qb.y & qc.y & qd.y & qe.y & qf.y;
                unsigned int o1 = q0.y | q1.y | q2.y | q3.y | q4.y | q5.y | q6.y | q7.y
                                | q8.y | q9.y | qa.y | qb.y | qc.y | qd.y | qe.y | qf.y;
                ok = ((m0 >> 16) == tag) & ((o0 >> 16) == tag)
                   & ((m1 >> 16) == tag) & ((o1 >> 16) == tag);
            } while (!ok);
            float* hd = &hlds[hrow * 516 + hc0];
            hd[32 * 0]  = __uint_as_float((q0.x << 16) | (q0.y & 0xFFFFu));
            hd[32 * 1]  = __uint_as_float((q1.x << 16) | (q1.y & 0xFFFFu));
            hd[32 * 2]  = __uint_as_float((q2.x << 16) | (q2.y & 0xFFFFu));
            hd[32 * 3]  = __uint_as_float((q3.x << 16) | (q3.y & 0xFFFFu));
            hd[32 * 4]  = __uint_as_float((q4.x << 16) | (q4.y & 0xFFFFu));
            hd[32 * 5]  = __uint_as_float((q5.x << 16) | (q5.y & 0xFFFFu));
            hd[32 * 6]  = __uint_as_float((q6.x << 16) | (q6.y & 0xFFFFu));
            hd[32 * 7]  = __uint_as_float((q7.x << 16) | (q7.y & 0xFFFFu));
            hd[32 * 8]  = __uint_as_float((q8.x << 16) | (q8.y & 0xFFFFu));
            hd[32 * 9]  = __uint_as_float((q9.x << 16) | (q9.y & 0xFFFFu));
            hd[32 * 10] = __uint_as_float((qa.x << 16) | (qa.y & 0xFFFFu));
            hd[32 * 11] = __uint_as_float((qb.x << 16) | (qb.y & 0xFFFFu));
            hd[32 * 12] = __uint_as_float((qc.x << 16) | (qc.y & 0xFFFFu));
            hd[32 * 13] = __uint_as_float((qd.x << 16) | (qd.y & 0xFFFFu));
            hd[32 * 14] = __uint_as_float((qe.x << 16) | (qe.y & 0xFFFFu));
            hd[32 * 15] = __uint_as_float((qf.x << 16) | (qf.y & 0xFFFFu));
        }
        gx_cur = gx_nxt;
    }
}

// ---------------- final projection: bf16 MFMA GEMM, C = A*B^T + bias ----------------
// A: hid bf16 [M][K]. B: W2 fp32 [N][K] (converted to bf16 during staging). C fp32.
__global__ __launch_bounds__(256) void gemm_bf16(
    const ushort_t* __restrict__ A,
    const float* __restrict__ B,
    const float* __restrict__ bias,
    float* __restrict__ C, int M, int N, int K)
{
    __shared__ ushort_t As[128 * 72];
    __shared__ ushort_t Bs[128 * 72];
    const int tid = threadIdx.x;
    const int bm = blockIdx.x * 128, bn = blockIdx.y * 128;
    const int lane = tid & 63, wave = tid >> 6;
    const int wm = (wave & 1) * 64, wn = (wave >> 1) * 64;
    const int lr = lane & 15, lk = (lane >> 4) * 8;
    const int srow = tid >> 3, sch = tid & 7;
    f32x4 acc[4][4] = {};

    for (int k0 = 0; k0 < K; k0 += 64) {
        #pragma unroll
        for (int rr = 0; rr < 4; rr++) {
            int row = srow + rr * 32;
            const ushort_t* as = A + (size_t)(bm + row) * K + k0 + sch * 8;
            *(int4*)&As[row * 72 + sch * 8] = *(const int4*)as;
            const float* bs = B + (size_t)(bn + row) * K + k0 + sch * 8;
            float4 f0 = *(const float4*)bs;
            float4 f1 = *(const float4*)(bs + 4);
            int4 pk;
            pk.x = (int)f2bf(f0.x) | ((int)f2bf(f0.y) << 16);
            pk.y = (int)f2bf(f0.z) | ((int)f2bf(f0.w) << 16);
            pk.z = (int)f2bf(f1.x) | ((int)f2bf(f1.y) << 16);
            pk.w = (int)f2bf(f1.z) | ((int)f2bf(f1.w) << 16);
            *(int4*)&Bs[row * 72 + sch * 8] = pk;
        }
        __syncthreads();
        #pragma unroll
        for (int k2 = 0; k2 < 64; k2 += 32) {
            bf16x8 a[4], bfr[4];
            #pragma unroll
            for (int i = 0; i < 4; i++)
                a[i] = *(const bf16x8*)&As[(wm + i * 16 + lr) * 72 + k2 + lk];
            #pragma unroll
            for (int j = 0; j < 4; j++)
                bfr[j] = *(const bf16x8*)&Bs[(wn + j * 16 + lr) * 72 + k2 + lk];
            #pragma unroll
            for (int i = 0; i < 4; i++)
                #pragma unroll
                for (int j = 0; j < 4; j++)
                    acc[i][j] = __builtin_amdgcn_mfma_f32_16x16x32_bf16(a[i], bfr[j], acc[i][j], 0, 0, 0);
        }
        __syncthreads();
    }
    const int r0 = (lane >> 4) * 4;
    #pragma unroll
    for (int j = 0; j < 4; j++) {
        int col = bn + wn + j * 16 + lr;
        float bv = bias[col];
        #pragma unroll
        for (int i = 0; i < 4; i++) {
            int row = bm + wm + i * 16 + r0;
            #pragma unroll
            for (int q = 0; q < 4; q++)
                C[(size_t)(row + q) * N + col] = acc[i][j][q] + bv;
        }
    }
}

extern "C" void kernel_launch(void* const* d_in, const int* in_sizes, int n_in,
                              void* d_out, int out_size, void* d_ws, size_t ws_size,
                              hipStream_t stream) {
    const int*   src      = (const int*)d_in[0];
    const int*   tgt      = (const int*)d_in[1];
    const float* enc_emb  = (const float*)d_in[2];
    const float* dec_emb  = (const float*)d_in[3];
    const float* eWih0    = (const float*)d_in[4];
    const float* eWhh0    = (const float*)d_in[5];
    const float* eb0      = (const float*)d_in[6];
    const float* eWih1    = (const float*)d_in[7];
    const float* eWhh1    = (const float*)d_in[8];
    const float* eb1      = (const float*)d_in[9];
    const float* dWih0    = (const float*)d_in[10];
    const float* dWhh0    = (const float*)d_in[11];
    const float* db0      = (const float*)d_in[12];
    const float* dWih1    = (const float*)d_in[13];
    const float* dWhh1    = (const float*)d_in[14];
    const float* db1      = (const float*)d_in[15];
    const float* pW1      = (const float*)d_in[16];
    const float* pb1      = (const float*)d_in[17];
    const float* pW2      = (const float*)d_in[18];
    const float* pb2      = (const float*)d_in[19];
    float* out = (float*)d_out;

    // workspace carve (small persistent buffers)
    float* fws   = (float*)d_ws;
    float* zeros = fws;                        // 512 f (padded to 1024)
    float* cT0   = fws + 2048;                 // 16384 f
    float* cT1   = cT0 + 16384;
    float* ctx   = cT1 + 16384;
    float* ctxW  = ctx + 16384;                // 65536 f
    ushort_t* hid = (ushort_t*)(ctxW + 65536); // 2048*512 bf16

    // d_out scratch (all dead before final projection writes everything)
    float* G0  = out;                 // 2048*2048 gate buffers
    float* G1  = G0 + 4194304;
    float* G2  = G1 + 4194304;
    float* G3  = G2 + 4194304;
    float* xe  = G3 + 4194304;        // 2048*256
    float* xd  = xe + 524288;
    float* e0  = xd + 524288;         // 2048*512
    float* e1  = e0 + 1048576;
    float* d0  = e1 + 1048576;
    float* d1v = d0 + 1048576;
    uint2* ring = (uint2*)(d1v + 1048576); // [64][32][512] tagged h (8 MB)

    zero_init<<<1, 256, 0, stream>>>(zeros);
    gather_rows<<<2048, 64, 0, stream>>>(src, enc_emb, xe);
    gather_rows<<<2048, 64, 0, stream>>>(tgt, dec_emb, xd);

    // encoder layer 0
    gemm_f32<<<dim3(32, 32), 256, 0, stream>>>(xe, 256, eWih0, 256, eb0, G0, 2048, 2048, 2048, 256, 0);
    lstm_scan<<<256, 256, 0, stream>>>(G0, nullptr, eWhh0, zeros, 0, zeros, 0, e0, cT0, ring, 0);
    // encoder layer 1
    gemm_f32<<<dim3(32, 32), 256, 0, stream>>>(e0, 512, eWih1, 512, eb1, G1, 2048, 2048, 2048, 512, 0);
    lstm_scan<<<256, 256, 0, stream>>>(G1, nullptr, eWhh1, zeros, 0, zeros, 0, e1, cT1, ring, 64);
    // context
    mean_ctx<<<64, 256, 0, stream>>>(e1, ctx);
    // decoder layer 0: gates = xd*Wih[:, :256]^T + b + ctx*Wih[:, 256:]^T (added in scan)
    gemm_f32<<<dim3(32, 32), 256, 0, stream>>>(xd, 256, dWih0, 768, db0, G2, 2048, 2048, 2048, 256, 0);
    gemm_f32<<<dim3(32, 1), 256, 0, stream>>>(ctx, 512, dWih0 + 256, 768, nullptr, ctxW, 2048, 32, 2048, 512, 0);
    lstm_scan<<<256, 256, 0, stream>>>(G2, ctxW, dWhh0, e0 + 63 * 512, 64 * 512, cT0, 512, d0, nullptr, ring, 128);
    // decoder layer 1
    gemm_f32<<<dim3(32, 32), 256, 0, stream>>>(d0, 512, dWih1, 512, db1, G3, 2048, 2048, 2048, 512, 0);
    lstm_scan<<<256, 256, 0, stream>>>(G3, nullptr, dWhh1, e1 + 63 * 512, 64 * 512, cT1, 512, d1v, nullptr, ring, 192);
    // projection: hid = tanh(d1*W1^T + b1) stored bf16; logits = hid*W2^T + b2 (MFMA)
    gemm_f32<<<dim3(8, 32), 256, 0, stream>>>(d1v, 512, pW1, 512, pb1, hid, 512, 2048, 512, 512, 2);
    gemm_bf16<<<dim3(16, 250), 256, 0, stream>>>(hid, pW2, pb2, out, 2048, 32000, 512);
}